// Round 7
// baseline (893.418 us; speedup 1.0000x reference)
//
#include <hip/hip_runtime.h>
#include <hip/hip_bf16.h>
#include <math.h>

#define B_ 4
#define T_ 1024
#define D_ 1024
#define H_ 4
#define DK_ 256
#define DV_ 512
#define KC_ 4

typedef __attribute__((ext_vector_type(4))) float floatx4;
typedef __attribute__((ext_vector_type(8))) short short8_t;

__device__ __forceinline__ unsigned short f2b(float f) {
    __hip_bfloat16 h = __float2bfloat16(f);
    return *(unsigned short*)&h;
}
__device__ __forceinline__ float b2f(unsigned short u) {
    unsigned int x = ((unsigned int)u) << 16;
    return *(float*)&x;
}

// ---------------- f32 -> bf16 convert (vectorized, 4 elems/thread) -------------
__global__ __launch_bounds__(256) void tob16_kernel(const float* __restrict__ in,
                                                    unsigned short* __restrict__ out) {
    int i = blockIdx.x * 256 + threadIdx.x;
    float4 f = ((const float4*)in)[i];
    ushort4 u;
    u.x = f2b(f.x); u.y = f2b(f.y); u.z = f2b(f.z); u.w = f2b(f.w);
    ((ushort4*)out)[i] = u;
}

// ---------------- W[K,N] f32 -> Wt[N,K] bf16 (LDS-tiled transpose) -------------
__global__ __launch_bounds__(256) void transpose_bf16_kernel(const float* __restrict__ W,
                                                             unsigned short* __restrict__ Wt,
                                                             int K, int N) {
    __shared__ float Ls[32][33];
    int tx = threadIdx.x & 31, ty = threadIdx.x >> 5;  // ty 0..7
    int k0 = blockIdx.y * 32, n0 = blockIdx.x * 32;
#pragma unroll
    for (int i = 0; i < 4; ++i)
        Ls[ty * 4 + i][tx] = W[(size_t)(k0 + ty * 4 + i) * N + n0 + tx];
    __syncthreads();
#pragma unroll
    for (int i = 0; i < 4; ++i)
        Wt[(size_t)(n0 + ty * 4 + i) * K + k0 + tx] = f2b(Ls[tx][ty * 4 + i]);
}

// ---------------- bf16 MFMA GEMM: C[M,N]f32 = A[M,K]bf16 * Bt[N,K]bf16 ---------
__global__ __launch_bounds__(256) void gemm_bf16_kernel(const unsigned short* __restrict__ A,
                                                        const unsigned short* __restrict__ Bt,
                                                        float* __restrict__ C,
                                                        int M, int N, int K) {
    __shared__ unsigned short As[128 * 40];
    __shared__ unsigned short Bs[128 * 40];
    int tid = threadIdx.x;
    int m0 = blockIdx.y * 128, n0 = blockIdx.x * 128;
    int w = tid >> 6, lane = tid & 63;
    int wm = w >> 1, wn = w & 1;
    floatx4 acc[4][4] = {};

    int c0 = tid, c1 = 256 + tid;
    int r0 = c0 >> 2, col0 = (c0 & 3) * 8;
    int r1 = c1 >> 2, col1 = (c1 & 3) * 8;
    int koff = (lane >> 4) * 8;

    for (int k0 = 0; k0 < K; k0 += 32) {
        short8_t a0 = *(const short8_t*)&A[(size_t)(m0 + r0) * K + k0 + col0];
        short8_t a1 = *(const short8_t*)&A[(size_t)(m0 + r1) * K + k0 + col1];
        short8_t b0 = *(const short8_t*)&Bt[(size_t)(n0 + r0) * K + k0 + col0];
        short8_t b1 = *(const short8_t*)&Bt[(size_t)(n0 + r1) * K + k0 + col1];
        __syncthreads();
        *(short8_t*)&As[r0 * 40 + col0] = a0;
        *(short8_t*)&As[r1 * 40 + col1] = a1;
        *(short8_t*)&Bs[r0 * 40 + col0] = b0;
        *(short8_t*)&Bs[r1 * 40 + col1] = b1;
        __syncthreads();
        short8_t af[4], bf[4];
#pragma unroll
        for (int f = 0; f < 4; ++f) {
            af[f] = *(const short8_t*)&As[(wm * 64 + f * 16 + (lane & 15)) * 40 + koff];
            bf[f] = *(const short8_t*)&Bs[(wn * 64 + f * 16 + (lane & 15)) * 40 + koff];
        }
#pragma unroll
        for (int i = 0; i < 4; ++i)
#pragma unroll
            for (int j = 0; j < 4; ++j)
                acc[i][j] = __builtin_amdgcn_mfma_f32_16x16x32_bf16(af[i], bf[j], acc[i][j], 0, 0, 0);
    }
#pragma unroll
    for (int i = 0; i < 4; ++i) {
        int row = m0 + wm * 64 + i * 16 + (lane >> 4) * 4;
#pragma unroll
        for (int j = 0; j < 4; ++j) {
            int col = n0 + wn * 64 + j * 16 + (lane & 15);
#pragma unroll
            for (int r = 0; r < 4; ++r)
                C[(size_t)(row + r) * N + col] = acc[i][j][r];
        }
    }
}

// ---------------- beta = sigmoid(x@Wb), g = -exp(A_log)*softplus(x@Wa+dt_bias) --
__global__ __launch_bounds__(256) void betag_kernel(const float* __restrict__ x,
                                                    const float* __restrict__ Wb,
                                                    const float* __restrict__ Wa,
                                                    const float* __restrict__ A_log,
                                                    const float* __restrict__ dt_bias,
                                                    float* __restrict__ beta,
                                                    float* __restrict__ g) {
    int row = blockIdx.x;  // b*T + t
    int tid = threadIdx.x;
    const float* xr = x + (size_t)row * D_;
    float pb[H_] = {}, pa[H_] = {};
    for (int j = 0; j < D_ / 256; ++j) {
        int d = j * 256 + tid;
        float xv = xr[d];
#pragma unroll
        for (int h = 0; h < H_; ++h) {
            pb[h] = fmaf(xv, Wb[d * H_ + h], pb[h]);
            pa[h] = fmaf(xv, Wa[d * H_ + h], pa[h]);
        }
    }
#pragma unroll
    for (int h = 0; h < H_; ++h) {
        for (int off = 32; off; off >>= 1) {
            pb[h] += __shfl_down(pb[h], off);
            pa[h] += __shfl_down(pa[h], off);
        }
    }
    __shared__ float ws[4][2][H_];
    int lane = tid & 63, w = tid >> 6;
    if (lane == 0) {
#pragma unroll
        for (int h = 0; h < H_; ++h) {
            ws[w][0][h] = pb[h];
            ws[w][1][h] = pa[h];
        }
    }
    __syncthreads();
    if (tid < H_) {
        float db = ws[0][0][tid] + ws[1][0][tid] + ws[2][0][tid] + ws[3][0][tid];
        float da = ws[0][1][tid] + ws[1][1][tid] + ws[2][1][tid] + ws[3][1][tid];
        beta[(size_t)row * H_ + tid] = 1.f / (1.f + expf(-db));
        float z = da + dt_bias[tid];
        float sp = (z > 20.f) ? z : log1pf(expf(z));
        g[(size_t)row * H_ + tid] = -expf(A_log[tid]) * sp;
    }
}

// ---------------- causal depthwise conv + silu + l2norm (q, k) -> bf16 ---------
// raw points at the q/k column block of the fused projection matrix (row stride S).
__global__ __launch_bounds__(256) void convqk_kernel(const float* __restrict__ raw,
                                                     int stride,
                                                     const float* __restrict__ w,
                                                     __hip_bfloat16* __restrict__ out) {
    int bt_h = blockIdx.x;
    int h = bt_h & (H_ - 1);
    int row = bt_h >> 2;
    int t = row & (T_ - 1);
    int c = threadIdx.x;
    int C = h * DK_ + c;
    float acc = 0.f;
#pragma unroll
    for (int i = 0; i < KC_; ++i) {
        int tt = t - (KC_ - 1) + i;
        if (tt >= 0)
            acc = fmaf(raw[(size_t)(row - (KC_ - 1) + i) * stride + C], w[C * KC_ + i], acc);
    }
    float s = acc / (1.f + expf(-acc));
    float ss = s * s;
    for (int off = 32; off; off >>= 1) ss += __shfl_down(ss, off);
    __shared__ float ws4[4];
    int lane = threadIdx.x & 63, wv = threadIdx.x >> 6;
    if (lane == 0) ws4[wv] = ss;
    __syncthreads();
    float tot = ws4[0] + ws4[1] + ws4[2] + ws4[3];
    float r = rsqrtf(tot + 1e-6f);
    out[(size_t)bt_h * DK_ + c] = __float2bfloat16(s * r);
}

// ---------------- causal depthwise conv + silu (v) -> bf16 ---------------------
__global__ __launch_bounds__(256) void convv_kernel(const float* __restrict__ raw,
                                                    int stride,
                                                    const float* __restrict__ w,
                                                    __hip_bfloat16* __restrict__ out) {
    size_t idx = (size_t)blockIdx.x * 256 + threadIdx.x;
    int C = idx & (H_ * DV_ - 1);
    int row = (int)(idx >> 11);
    int t = row & (T_ - 1);
    float acc = 0.f;
#pragma unroll
    for (int i = 0; i < KC_; ++i) {
        int tt = t - (KC_ - 1) + i;
        if (tt >= 0)
            acc = fmaf(raw[(size_t)(row - (KC_ - 1) + i) * stride + C], w[C * KC_ + i], acc);
    }
    out[idx] = __float2bfloat16(acc / (1.f + expf(-acc)));
}

// ---------------- chunk prep (lean: no solves -> no spills) --------------------
__global__ __launch_bounds__(256) void prep_kernel(const unsigned short* __restrict__ qn,
                                                   const unsigned short* __restrict__ kn,
                                                   const float* __restrict__ gl,
                                                   const float* __restrict__ betal,
                                                   float* __restrict__ Afg,
                                                   unsigned short* __restrict__ KdTg,
                                                   unsigned short* __restrict__ Pg,
                                                   float* __restrict__ lambg,
                                                   float* __restrict__ scl0,
                                                   float* __restrict__ scl1) {
    int blk = blockIdx.x;
    int nc = blk & 31, bh = blk >> 5;
    int b = bh >> 2, h = bh & 3;
    int t0 = nc * 32;
    int tid = threadIdx.x, w = tid >> 6, l = tid & 63;
    int vl = l & 15, hq = l >> 4;
    size_t cb = (size_t)bh * 32 + nc;

    __shared__ __align__(16) unsigned short Kt[32][264];
    __shared__ float gcs[32], bets[32], kdec[32];

    if (tid < 32) {
        size_t base = ((size_t)(b * T_ + t0 + tid) * H_ + h);
        float gv = gl[base];
        float bv = betal[base];
        float x = gv;
#pragma unroll
        for (int off = 1; off < 32; off <<= 1) {
            float y = __shfl_up(x, off);
            if (tid >= off) x += y;
        }
        gcs[tid] = x;
        float lm = expf(x);
        bets[tid] = bv;
        float tot = __shfl(x, 31);
        kdec[tid] = expf(tot - x);
        lambg[cb * 32 + tid] = lm;
        scl0[cb * 32 + tid] = bv * lm;
        scl1[cb * 32 + tid] = bv;
    }
    __syncthreads();
    {
        int r = tid >> 3, c8 = (tid & 7) * 32;
        size_t gbase = ((size_t)(b * T_ + t0 + r) * H_ + h) * DK_;
#pragma unroll
        for (int ii = 0; ii < 4; ++ii)
            *(short8_t*)&Kt[r][c8 + ii * 8] = *(const short8_t*)&kn[gbase + c8 + ii * 8];
    }
    __syncthreads();
    if (w < 3) {
        int mt = (w == 0) ? 0 : 1;
        int nt = (w == 2) ? 1 : 0;
        floatx4 acc = {};
#pragma unroll
        for (int k0 = 0; k0 < 8; ++k0) {
            short8_t a = *(const short8_t*)&Kt[mt * 16 + vl][k0 * 32 + hq * 8];
            short8_t bb = *(const short8_t*)&Kt[nt * 16 + vl][k0 * 32 + hq * 8];
            acc = __builtin_amdgcn_mfma_f32_16x16x32_bf16(a, bb, acc, 0, 0, 0);
        }
#pragma unroll
        for (int r = 0; r < 4; ++r) {
            int i = mt * 16 + 4 * hq + r, j = nt * 16 + vl;
            Afg[cb * 1024 + i * 32 + j] = (j < i) ? bets[i] * expf(gcs[i] - gcs[j]) * acc[r] : 0.f;
        }
        floatx4 accp = {};
#pragma unroll
        for (int k0 = 0; k0 < 8; ++k0) {
            size_t qrow = ((size_t)(b * T_ + t0 + mt * 16 + vl) * H_ + h) * DK_ + k0 * 32 + hq * 8;
            short8_t a = *(const short8_t*)&qn[qrow];
            short8_t bb = *(const short8_t*)&Kt[nt * 16 + vl][k0 * 32 + hq * 8];
            accp = __builtin_amdgcn_mfma_f32_16x16x32_bf16(a, bb, accp, 0, 0, 0);
        }
#pragma unroll
        for (int r = 0; r < 4; ++r) {
            int i = mt * 16 + 4 * hq + r, j = nt * 16 + vl;
            Pg[cb * 1024 + i * 32 + j] = f2b((j <= i) ? expf(gcs[i] - gcs[j]) * accp[r] : 0.f);
        }
    } else {
#pragma unroll
        for (int ii = 0; ii < 4; ++ii)
            Pg[cb * 1024 + (l >> 2) * 32 + 16 + (l & 3) * 4 + ii] = 0;
    }
    {
#pragma unroll
        for (int it = 0; it < 16; ++it) {
            int uidx = it * 256 + tid;
            int k = uidx >> 4, cp = (uidx & 15) * 2;
            float kv0 = b2f(Kt[cp][k]) * kdec[cp];
            float kv1 = b2f(Kt[cp + 1][k]) * kdec[cp + 1];
            unsigned int pk = (unsigned int)f2b(kv0) | ((unsigned int)f2b(kv1) << 16);
            ((unsigned int*)KdTg)[cb * 4096 + uidx] = pk;
        }
    }
}

// ---------------- triangular solves: (I+A)u = rhs, one column per thread -------
// grid (3, 512): part 0 -> Wp (rhs = scl0.K), parts 1,2 -> U (rhs = scl1.V).
// __launch_bounds__(256,4): cap VGPR at 128 -> no spill (round-6 lesson:
// uncapped, the scheduler hoists hundreds of LDS loads -> 256 VGPR + 85MB spill).
__global__ __launch_bounds__(256, 4) void solve_kernel(const unsigned short* __restrict__ kn,
                                                       const unsigned short* __restrict__ vn,
                                                       const float* __restrict__ Afg,
                                                       const float* __restrict__ scl0,
                                                       const float* __restrict__ scl1,
                                                       unsigned short* __restrict__ Wpg,
                                                       unsigned short* __restrict__ Ug) {
    int part = blockIdx.x;   // 0..2
    int cbi = blockIdx.y;    // 0..511
    int bh = cbi >> 5, nc = cbi & 31;
    int b = bh >> 2, h = bh & 3;
    int t0 = nc * 32;
    int tid = threadIdx.x;

    __shared__ float Af[32][33];
    __shared__ float s0[32];
#pragma unroll
    for (int i = 0; i < 4; ++i) {
        int e = i * 256 + tid;
        Af[e >> 5][e & 31] = Afg[(size_t)cbi * 1024 + e];
    }
    if (tid < 32)
        s0[tid] = (part == 0) ? scl0[(size_t)cbi * 32 + tid] : scl1[(size_t)cbi * 32 + tid];
    __syncthreads();

    float u[32];
    if (part == 0) {
#pragma unroll
        for (int r = 0; r < 32; ++r)
            u[r] = s0[r] * b2f(kn[((size_t)(b * T_ + t0 + r) * H_ + h) * DK_ + tid]);
    } else {
        int col = (part - 1) * 256 + tid;
#pragma unroll
        for (int r = 0; r < 32; ++r)
            u[r] = s0[r] * b2f(vn[((size_t)(b * T_ + t0 + r) * H_ + h) * DV_ + col]);
    }
#pragma unroll
    for (int r = 1; r < 32; ++r) {
        float a = 0.f;
#pragma unroll
        for (int l2 = 0; l2 < r; ++l2)
            a = fmaf(Af[r][l2], u[l2], a);
        u[r] -= a;
    }
    if (part == 0) {
#pragma unroll
        for (int r = 0; r < 32; ++r)
            Wpg[(size_t)cbi * 8192 + r * 256 + tid] = f2b(u[r]);
    } else {
        int col = (part - 1) * 256 + tid;
#pragma unroll
        for (int r = 0; r < 32; ++r)
            Ug[((size_t)cbi * 32 + r) * 512 + col] = f2b(u[r]);
    }
}

// ---------------- sequential pass: 512 blocks x 4 waves (k-split) --------------
__global__ __launch_bounds__(256) void seq_kernel(const unsigned short* __restrict__ qn,
                                                  const unsigned short* __restrict__ Wpg,
                                                  const unsigned short* __restrict__ KdTg,
                                                  const unsigned short* __restrict__ Pg,
                                                  const unsigned short* __restrict__ Ug,
                                                  const float* __restrict__ lambg,
                                                  unsigned short* __restrict__ o) {
    int blk = blockIdx.x;
    int vg = blk & 31, bh = blk >> 5;
    int b = bh >> 2, h = bh & 3;
    int tid = threadIdx.x;
    int w = tid >> 6, l = tid & 63;
    int vl = l & 15, hq = l >> 4;
    int v0 = vg * 16;

    __shared__ float Pu[4][32][17];
    __shared__ float Po[4][32][17];
    __shared__ __align__(16) unsigned short Ru[16][40];
    __shared__ float R2[4][64][17];

    float S[2][8] = {};

    for (int nc = 0; nc < 32; ++nc) {
        size_t cb = (size_t)bh * 32 + nc;
        int t0 = nc * 32;
        int ur_row = 8 * w + 2 * hq;
        float Ur0 = b2f(Ug[(cb * 32 + ur_row) * 512 + v0 + vl]);
        float Ur1 = b2f(Ug[(cb * 32 + ur_row + 1) * 512 + v0 + vl]);
        float lamC = lambg[cb * 32 + 31];
        float lmb[4];
        if (w < 2) {
#pragma unroll
            for (int r = 0; r < 4; ++r)
                lmb[r] = lambg[cb * 32 + 16 * w + 4 * hq + r];
        }
        short8_t bhi[2], blo[2];
#pragma unroll
        for (int kt = 0; kt < 2; ++kt)
#pragma unroll
            for (int j = 0; j < 8; ++j) {
                float sv = S[kt][j];
                unsigned short hh = f2b(sv);
                bhi[kt][j] = (short)hh;
                blo[kt][j] = (short)f2b(sv - b2f(hh));
            }
        floatx4 ua0 = {}, ua1 = {}, oa0 = {}, oa1 = {};
        const unsigned short* Wpc = Wpg + cb * 8192;
#pragma unroll
        for (int kt = 0; kt < 2; ++kt) {
            int kofs = w * 64 + kt * 32 + hq * 8;
            short8_t wa0 = *(const short8_t*)&Wpc[vl * 256 + kofs];
            short8_t wa1 = *(const short8_t*)&Wpc[(16 + vl) * 256 + kofs];
            short8_t qa0 = *(const short8_t*)&qn[((size_t)(b * T_ + t0 + vl) * H_ + h) * DK_ + kofs];
            short8_t qa1 = *(const short8_t*)&qn[((size_t)(b * T_ + t0 + 16 + vl) * H_ + h) * DK_ + kofs];
            ua0 = __builtin_amdgcn_mfma_f32_16x16x32_bf16(wa0, bhi[kt], ua0, 0, 0, 0);
            ua0 = __builtin_amdgcn_mfma_f32_16x16x32_bf16(wa0, blo[kt], ua0, 0, 0, 0);
            ua1 = __builtin_amdgcn_mfma_f32_16x16x32_bf16(wa1, bhi[kt], ua1, 0, 0, 0);
            ua1 = __builtin_amdgcn_mfma_f32_16x16x32_bf16(wa1, blo[kt], ua1, 0, 0, 0);
            oa0 = __builtin_amdgcn_mfma_f32_16x16x32_bf16(qa0, bhi[kt], oa0, 0, 0, 0);
            oa0 = __builtin_amdgcn_mfma_f32_16x16x32_bf16(qa0, blo[kt], oa0, 0, 0, 0);
            oa1 = __builtin_amdgcn_mfma_f32_16x16x32_bf16(qa1, bhi[kt], oa1, 0, 0, 0);
            oa1 = __builtin_amdgcn_mfma_f32_16x16x32_bf16(qa1, blo[kt], oa1, 0, 0, 0);
        }
#pragma unroll
        for (int r = 0; r < 4; ++r) {
            Pu[w][4 * hq + r][vl] = ua0[r];
            Pu[w][16 + 4 * hq + r][vl] = ua1[r];
            Po[w][4 * hq + r][vl] = oa0[r];
            Po[w][16 + 4 * hq + r][vl] = oa1[r];
        }
        __syncthreads();
#pragma unroll
        for (int j = 0; j < 2; ++j) {
            int r = ur_row + j;
            float s = Pu[0][r][vl] + Pu[1][r][vl] + Pu[2][r][vl] + Pu[3][r][vl];
            Ru[vl][r] = f2b(((j == 0) ? Ur0 : Ur1) - s);
        }
        __syncthreads();
        short8_t uf = *(const short8_t*)&Ru[vl][8 * hq];
        if (w < 2) {
            short8_t p = *(const short8_t*)&Pg[cb * 1024 + (w * 16 + vl) * 32 + hq * 8];
            floatx4 pa = {};
            pa = __builtin_amdgcn_mfma_f32_16x16x32_bf16(p, uf, pa, 0, 0, 0);
#pragma unroll
            for (int r = 0; r < 4; ++r) {
                int row = 16 * w + 4 * hq + r;
                float po = Po[0][row][vl] + Po[1][row][vl] + Po[2][row][vl] + Po[3][row][vl];
                o[((size_t)(b * T_ + t0 + row) * H_ + h) * DV_ + v0 + vl] =
                    f2b(0.0625f * (lmb[r] * po + pa[r]));
            }
        }
        const unsigned short* Kc = KdTg + cb * 8192;
#pragma unroll
        for (int kt = 0; kt < 4; ++kt) {
            short8_t ka = *(const short8_t*)&Kc[(w * 64 + kt * 16 + vl) * 32 + hq * 8];
            floatx4 sa = {};
            sa = __builtin_amdgcn_mfma_f32_16x16x32_bf16(ka, uf, sa, 0, 0, 0);
#pragma unroll
            for (int r = 0; r < 4; ++r)
                R2[w][kt * 16 + 4 * hq + r][vl] = sa[r];
        }
#pragma unroll
        for (int kt = 0; kt < 2; ++kt)
#pragma unroll
            for (int j = 0; j < 8; ++j)
                S[kt][j] = fmaf(lamC, S[kt][j], R2[w][kt * 32 + hq * 8 + j][vl]);
        __syncthreads();
    }
}

// ---------------- gated RMSNorm, in-place on bf16 o ----------------------------
__global__ __launch_bounds__(256) void gnorm_kernel(unsigned short* __restrict__ o,
                                                    const float* __restrict__ gate,
                                                    const float* __restrict__ norm_w) {
    int bth = blockIdx.x;
    int tid = threadIdx.x;
    unsigned short* orow = o + (size_t)bth * DV_;
    float v0 = b2f(orow[tid]), v1 = b2f(orow[256 + tid]);
    float ss = v0 * v0 + v1 * v1;
    for (int off = 32; off; off >>= 1) ss += __shfl_down(ss, off);
    __shared__ float ws4[4];
    int lane = tid & 63, wv = tid >> 6;
    if (lane == 0) ws4[wv] = ss;
    __syncthreads();
    float tot = ws4[0] + ws4[1] + ws4[2] + ws4[3];
    float r = rsqrtf(tot * (1.f / DV_) + 1e-5f);
    float g0 = gate[(size_t)bth * DV_ + tid];
    float g1 = gate[(size_t)bth * DV_ + 256 + tid];
    orow[tid] = f2b(v0 * r * norm_w[tid] * (g0 / (1.f + expf(-g0))));
    orow[256 + tid] = f2b(v1 * r * norm_w[256 + tid] * (g1 / (1.f + expf(-g1))));
}

extern "C" void kernel_launch(void* const* d_in, const int* in_sizes, int n_in,
                              void* d_out, int out_size, void* d_ws, size_t ws_size,
                              hipStream_t stream) {
    const float* x = (const float*)d_in[0];
    const float* Wq = (const float*)d_in[1];
    const float* Wk = (const float*)d_in[2];
    const float* Wv = (const float*)d_in[3];
    const float* cqw = (const float*)d_in[4];
    const float* ckw = (const float*)d_in[5];
    const float* cvw = (const float*)d_in[6];
    const float* Wb = (const float*)d_in[7];
    const float* Wa = (const float*)d_in[8];
    const float* A_log = (const float*)d_in[9];
    const float* dt_bias = (const float*)d_in[10];
    const float* Wg = (const float*)d_in[11];
    const float* norm_w = (const float*)d_in[12];
    const float* Wo = (const float*)d_in[13];
    float* out = (float*)d_out;

    float* ws = (float*)d_ws;
    const size_t M1 = (size_t)1024 * 1024;
    // lifetime-ordered regions (f32 offsets), peak ~30.1M floats:
    float* praw = ws;                                        // [0,16M) fused qkv gemm out (cols: q 0-1023, k 1024-2047, v 2048-4095)
    float* graw = ws;                                        // [0,8M)  gate gemm out (praw dead after convs), live to gnorm
    unsigned short* xb = (unsigned short*)(ws + 16 * M1);    // [16,18M) dead after g-gemm
    unsigned short* WcatT = (unsigned short*)(ws + 18 * M1); // [18,20M) [4096 rows,1024] bf16, dead after qkv gemm
    unsigned short* WgT = (unsigned short*)(ws + 20 * M1);   // [20,21M)
    unsigned short* WoT = (unsigned short*)(ws + 21 * M1);   // [21,22M) live to end
    unsigned short* qn = (unsigned short*)(ws + 22 * M1);    // [22,24M) live to seq
    unsigned short* kn = (unsigned short*)(ws + 24 * M1);    // [24,26M) dead after solve
    unsigned short* vn = (unsigned short*)(ws + 26 * M1);    // [26,30M) dead after solve
    float* g = ws + 30 * M1;                                 // [30M,+16K) dead after prep
    float* beta = g + 16384;                                 // +16K
    float* Afg = ws + 8 * M1;                                // [8,8.5M) dead after solve
    unsigned short* Pg = (unsigned short*)(ws + 8 * M1 + M1 / 2);   // [8.5,8.75M)
    unsigned short* KdTg = (unsigned short*)(ws + 9 * M1);   // [9,11M)
    float* lambg = ws + 11 * M1;                             // 16K
    float* scl0 = lambg + 16384;
    float* scl1 = scl0 + 16384;
    unsigned short* Wpg = (unsigned short*)(ws + 12 * M1);   // [12,14M)
    unsigned short* Ug = (unsigned short*)(ws + 14 * M1);    // [14,18M) (xb dead by then)
    unsigned short* ob = (unsigned short*)(ws + 24 * M1);    // [24,28M) seq out bf16 (kn/vn dead)

    dim3 blk(256);
    tob16_kernel<<<4096, blk, 0, stream>>>(x, xb);
    transpose_bf16_kernel<<<dim3(32, 32), blk, 0, stream>>>(Wq, WcatT, 1024, 1024);
    transpose_bf16_kernel<<<dim3(32, 32), blk, 0, stream>>>(Wk, WcatT + (size_t)1024 * 1024, 1024, 1024);
    transpose_bf16_kernel<<<dim3(64, 32), blk, 0, stream>>>(Wv, WcatT + (size_t)2048 * 1024, 1024, 2048);
    transpose_bf16_kernel<<<dim3(64, 32), blk, 0, stream>>>(Wg, WgT, 1024, 2048);
    transpose_bf16_kernel<<<dim3(32, 64), blk, 0, stream>>>(Wo, WoT, 2048, 1024);
    // fused q|k|v projection: [4096,1024] @ [1024,4096] -> praw (grid 32x32 = 1024 blocks)
    gemm_bf16_kernel<<<dim3(32, 32), blk, 0, stream>>>(xb, WcatT, praw, 4096, 4096, 1024);
    betag_kernel<<<4096, blk, 0, stream>>>(x, Wb, Wa, A_log, dt_bias, beta, g);
    convqk_kernel<<<16384, blk, 0, stream>>>(praw, 4096, cqw, (__hip_bfloat16*)qn);
    convqk_kernel<<<16384, blk, 0, stream>>>(praw + 1024, 4096, ckw, (__hip_bfloat16*)kn);
    convv_kernel<<<32768, blk, 0, stream>>>(praw + 2048, 4096, cvw, (__hip_bfloat16*)vn);
    // gate projection into freed praw region
    gemm_bf16_kernel<<<dim3(16, 32), blk, 0, stream>>>(xb, WgT, graw, 4096, 2048, 1024);
    prep_kernel<<<512, blk, 0, stream>>>(qn, kn, g, beta, Afg, KdTg, Pg, lambg, scl0, scl1);
    solve_kernel<<<dim3(3, 512), blk, 0, stream>>>(kn, vn, Afg, scl0, scl1, Wpg, Ug);
    seq_kernel<<<512, blk, 0, stream>>>(qn, Wpg, KdTg, Pg, Ug, lambg, ob);
    gnorm_kernel<<<16384, blk, 0, stream>>>(ob, graw, norm_w);
    gemm_bf16_kernel<<<dim3(8, 32), blk, 0, stream>>>(ob, WoT, out, 4096, 1024, 2048);
}

// Round 8
// 564.936 us; speedup vs baseline: 1.5815x; 1.5815x over previous
//
#include <hip/hip_runtime.h>
#include <hip/hip_bf16.h>
#include <math.h>

#define B_ 4
#define T_ 1024
#define D_ 1024
#define H_ 4
#define DK_ 256
#define DV_ 512
#define KC_ 4

typedef __attribute__((ext_vector_type(4))) float floatx4;
typedef __attribute__((ext_vector_type(8))) short short8_t;

__device__ __forceinline__ unsigned short f2b(float f) {
    __hip_bfloat16 h = __float2bfloat16(f);
    return *(unsigned short*)&h;
}
__device__ __forceinline__ float b2f(unsigned short u) {
    unsigned int x = ((unsigned int)u) << 16;
    return *(float*)&x;
}

// ---------------- f32 -> bf16 convert (vectorized, 4 elems/thread) -------------
__global__ __launch_bounds__(256) void tob16_kernel(const float* __restrict__ in,
                                                    unsigned short* __restrict__ out) {
    int i = blockIdx.x * 256 + threadIdx.x;
    float4 f = ((const float4*)in)[i];
    ushort4 u;
    u.x = f2b(f.x); u.y = f2b(f.y); u.z = f2b(f.z); u.w = f2b(f.w);
    ((ushort4*)out)[i] = u;
}

// ---------------- W[K,N] f32 -> Wt[N,K] bf16 (LDS-tiled transpose) -------------
__global__ __launch_bounds__(256) void transpose_bf16_kernel(const float* __restrict__ W,
                                                             unsigned short* __restrict__ Wt,
                                                             int K, int N) {
    __shared__ float Ls[32][33];
    int tx = threadIdx.x & 31, ty = threadIdx.x >> 5;  // ty 0..7
    int k0 = blockIdx.y * 32, n0 = blockIdx.x * 32;
#pragma unroll
    for (int i = 0; i < 4; ++i)
        Ls[ty * 4 + i][tx] = W[(size_t)(k0 + ty * 4 + i) * N + n0 + tx];
    __syncthreads();
#pragma unroll
    for (int i = 0; i < 4; ++i)
        Wt[(size_t)(n0 + ty * 4 + i) * K + k0 + tx] = f2b(Ls[tx][ty * 4 + i]);
}

// ---------------- bf16 MFMA GEMM: C[M,N]f32 = A[M,K]bf16 * Bt[N,K]bf16 ---------
__global__ __launch_bounds__(256) void gemm_bf16_kernel(const unsigned short* __restrict__ A,
                                                        const unsigned short* __restrict__ Bt,
                                                        float* __restrict__ C,
                                                        int M, int N, int K) {
    __shared__ unsigned short As[128 * 40];
    __shared__ unsigned short Bs[128 * 40];
    int tid = threadIdx.x;
    int m0 = blockIdx.y * 128, n0 = blockIdx.x * 128;
    int w = tid >> 6, lane = tid & 63;
    int wm = w >> 1, wn = w & 1;
    floatx4 acc[4][4] = {};

    int c0 = tid, c1 = 256 + tid;
    int r0 = c0 >> 2, col0 = (c0 & 3) * 8;
    int r1 = c1 >> 2, col1 = (c1 & 3) * 8;
    int koff = (lane >> 4) * 8;

    for (int k0 = 0; k0 < K; k0 += 32) {
        short8_t a0 = *(const short8_t*)&A[(size_t)(m0 + r0) * K + k0 + col0];
        short8_t a1 = *(const short8_t*)&A[(size_t)(m0 + r1) * K + k0 + col1];
        short8_t b0 = *(const short8_t*)&Bt[(size_t)(n0 + r0) * K + k0 + col0];
        short8_t b1 = *(const short8_t*)&Bt[(size_t)(n0 + r1) * K + k0 + col1];
        __syncthreads();
        *(short8_t*)&As[r0 * 40 + col0] = a0;
        *(short8_t*)&As[r1 * 40 + col1] = a1;
        *(short8_t*)&Bs[r0 * 40 + col0] = b0;
        *(short8_t*)&Bs[r1 * 40 + col1] = b1;
        __syncthreads();
        short8_t af[4], bf[4];
#pragma unroll
        for (int f = 0; f < 4; ++f) {
            af[f] = *(const short8_t*)&As[(wm * 64 + f * 16 + (lane & 15)) * 40 + koff];
            bf[f] = *(const short8_t*)&Bs[(wn * 64 + f * 16 + (lane & 15)) * 40 + koff];
        }
#pragma unroll
        for (int i = 0; i < 4; ++i)
#pragma unroll
            for (int j = 0; j < 4; ++j)
                acc[i][j] = __builtin_amdgcn_mfma_f32_16x16x32_bf16(af[i], bf[j], acc[i][j], 0, 0, 0);
    }
#pragma unroll
    for (int i = 0; i < 4; ++i) {
        int row = m0 + wm * 64 + i * 16 + (lane >> 4) * 4;
#pragma unroll
        for (int j = 0; j < 4; ++j) {
            int col = n0 + wn * 64 + j * 16 + (lane & 15);
#pragma unroll
            for (int r = 0; r < 4; ++r)
                C[(size_t)(row + r) * N + col] = acc[i][j][r];
        }
    }
}

// ---------------- beta = sigmoid(x@Wb), g = -exp(A_log)*softplus(x@Wa+dt_bias) --
__global__ __launch_bounds__(256) void betag_kernel(const float* __restrict__ x,
                                                    const float* __restrict__ Wb,
                                                    const float* __restrict__ Wa,
                                                    const float* __restrict__ A_log,
                                                    const float* __restrict__ dt_bias,
                                                    float* __restrict__ beta,
                                                    float* __restrict__ g) {
    int row = blockIdx.x;  // b*T + t
    int tid = threadIdx.x;
    const float* xr = x + (size_t)row * D_;
    float pb[H_] = {}, pa[H_] = {};
    for (int j = 0; j < D_ / 256; ++j) {
        int d = j * 256 + tid;
        float xv = xr[d];
#pragma unroll
        for (int h = 0; h < H_; ++h) {
            pb[h] = fmaf(xv, Wb[d * H_ + h], pb[h]);
            pa[h] = fmaf(xv, Wa[d * H_ + h], pa[h]);
        }
    }
#pragma unroll
    for (int h = 0; h < H_; ++h) {
        for (int off = 32; off; off >>= 1) {
            pb[h] += __shfl_down(pb[h], off);
            pa[h] += __shfl_down(pa[h], off);
        }
    }
    __shared__ float ws[4][2][H_];
    int lane = tid & 63, w = tid >> 6;
    if (lane == 0) {
#pragma unroll
        for (int h = 0; h < H_; ++h) {
            ws[w][0][h] = pb[h];
            ws[w][1][h] = pa[h];
        }
    }
    __syncthreads();
    if (tid < H_) {
        float db = ws[0][0][tid] + ws[1][0][tid] + ws[2][0][tid] + ws[3][0][tid];
        float da = ws[0][1][tid] + ws[1][1][tid] + ws[2][1][tid] + ws[3][1][tid];
        beta[(size_t)row * H_ + tid] = 1.f / (1.f + expf(-db));
        float z = da + dt_bias[tid];
        float sp = (z > 20.f) ? z : log1pf(expf(z));
        g[(size_t)row * H_ + tid] = -expf(A_log[tid]) * sp;
    }
}

// ---------------- causal depthwise conv + silu + l2norm (q, k) -> bf16 ---------
__global__ __launch_bounds__(256) void convqk_kernel(const float* __restrict__ raw,
                                                     int stride,
                                                     const float* __restrict__ w,
                                                     __hip_bfloat16* __restrict__ out) {
    int bt_h = blockIdx.x;
    int h = bt_h & (H_ - 1);
    int row = bt_h >> 2;
    int t = row & (T_ - 1);
    int c = threadIdx.x;
    int C = h * DK_ + c;
    float acc = 0.f;
#pragma unroll
    for (int i = 0; i < KC_; ++i) {
        int tt = t - (KC_ - 1) + i;
        if (tt >= 0)
            acc = fmaf(raw[(size_t)(row - (KC_ - 1) + i) * stride + C], w[C * KC_ + i], acc);
    }
    float s = acc / (1.f + expf(-acc));
    float ss = s * s;
    for (int off = 32; off; off >>= 1) ss += __shfl_down(ss, off);
    __shared__ float ws4[4];
    int lane = threadIdx.x & 63, wv = threadIdx.x >> 6;
    if (lane == 0) ws4[wv] = ss;
    __syncthreads();
    float tot = ws4[0] + ws4[1] + ws4[2] + ws4[3];
    float r = rsqrtf(tot + 1e-6f);
    out[(size_t)bt_h * DK_ + c] = __float2bfloat16(s * r);
}

// ---------------- causal depthwise conv + silu (v) -> bf16 ---------------------
__global__ __launch_bounds__(256) void convv_kernel(const float* __restrict__ raw,
                                                    int stride,
                                                    const float* __restrict__ w,
                                                    __hip_bfloat16* __restrict__ out) {
    size_t idx = (size_t)blockIdx.x * 256 + threadIdx.x;
    int C = idx & (H_ * DV_ - 1);
    int row = (int)(idx >> 11);
    int t = row & (T_ - 1);
    float acc = 0.f;
#pragma unroll
    for (int i = 0; i < KC_; ++i) {
        int tt = t - (KC_ - 1) + i;
        if (tt >= 0)
            acc = fmaf(raw[(size_t)(row - (KC_ - 1) + i) * stride + C], w[C * KC_ + i], acc);
    }
    out[idx] = __float2bfloat16(acc / (1.f + expf(-acc)));
}

// ---------------- chunk prep (lean: no solves -> no spills) --------------------
__global__ __launch_bounds__(256) void prep_kernel(const unsigned short* __restrict__ qn,
                                                   const unsigned short* __restrict__ kn,
                                                   const float* __restrict__ gl,
                                                   const float* __restrict__ betal,
                                                   float* __restrict__ Afg,
                                                   unsigned short* __restrict__ KdTg,
                                                   unsigned short* __restrict__ Pg,
                                                   float* __restrict__ lambg,
                                                   float* __restrict__ scl0,
                                                   float* __restrict__ scl1) {
    int blk = blockIdx.x;
    int nc = blk & 31, bh = blk >> 5;
    int b = bh >> 2, h = bh & 3;
    int t0 = nc * 32;
    int tid = threadIdx.x, w = tid >> 6, l = tid & 63;
    int vl = l & 15, hq = l >> 4;
    size_t cb = (size_t)bh * 32 + nc;

    __shared__ __align__(16) unsigned short Kt[32][264];
    __shared__ float gcs[32], bets[32], kdec[32];

    if (tid < 32) {
        size_t base = ((size_t)(b * T_ + t0 + tid) * H_ + h);
        float gv = gl[base];
        float bv = betal[base];
        float x = gv;
#pragma unroll
        for (int off = 1; off < 32; off <<= 1) {
            float y = __shfl_up(x, off);
            if (tid >= off) x += y;
        }
        gcs[tid] = x;
        float lm = expf(x);
        bets[tid] = bv;
        float tot = __shfl(x, 31);
        kdec[tid] = expf(tot - x);
        lambg[cb * 32 + tid] = lm;
        scl0[cb * 32 + tid] = bv * lm;
        scl1[cb * 32 + tid] = bv;
    }
    __syncthreads();
    {
        int r = tid >> 3, c8 = (tid & 7) * 32;
        size_t gbase = ((size_t)(b * T_ + t0 + r) * H_ + h) * DK_;
#pragma unroll
        for (int ii = 0; ii < 4; ++ii)
            *(short8_t*)&Kt[r][c8 + ii * 8] = *(const short8_t*)&kn[gbase + c8 + ii * 8];
    }
    __syncthreads();
    if (w < 3) {
        int mt = (w == 0) ? 0 : 1;
        int nt = (w == 2) ? 1 : 0;
        floatx4 acc = {};
#pragma unroll
        for (int k0 = 0; k0 < 8; ++k0) {
            short8_t a = *(const short8_t*)&Kt[mt * 16 + vl][k0 * 32 + hq * 8];
            short8_t bb = *(const short8_t*)&Kt[nt * 16 + vl][k0 * 32 + hq * 8];
            acc = __builtin_amdgcn_mfma_f32_16x16x32_bf16(a, bb, acc, 0, 0, 0);
        }
#pragma unroll
        for (int r = 0; r < 4; ++r) {
            int i = mt * 16 + 4 * hq + r, j = nt * 16 + vl;
            Afg[cb * 1024 + i * 32 + j] = (j < i) ? bets[i] * expf(gcs[i] - gcs[j]) * acc[r] : 0.f;
        }
        floatx4 accp = {};
#pragma unroll
        for (int k0 = 0; k0 < 8; ++k0) {
            size_t qrow = ((size_t)(b * T_ + t0 + mt * 16 + vl) * H_ + h) * DK_ + k0 * 32 + hq * 8;
            short8_t a = *(const short8_t*)&qn[qrow];
            short8_t bb = *(const short8_t*)&Kt[nt * 16 + vl][k0 * 32 + hq * 8];
            accp = __builtin_amdgcn_mfma_f32_16x16x32_bf16(a, bb, accp, 0, 0, 0);
        }
#pragma unroll
        for (int r = 0; r < 4; ++r) {
            int i = mt * 16 + 4 * hq + r, j = nt * 16 + vl;
            Pg[cb * 1024 + i * 32 + j] = f2b((j <= i) ? expf(gcs[i] - gcs[j]) * accp[r] : 0.f);
        }
    } else {
#pragma unroll
        for (int ii = 0; ii < 4; ++ii)
            Pg[cb * 1024 + (l >> 2) * 32 + 16 + (l & 3) * 4 + ii] = 0;
    }
    {
#pragma unroll
        for (int it = 0; it < 16; ++it) {
            int uidx = it * 256 + tid;
            int k = uidx >> 4, cp = (uidx & 15) * 2;
            float kv0 = b2f(Kt[cp][k]) * kdec[cp];
            float kv1 = b2f(Kt[cp + 1][k]) * kdec[cp + 1];
            unsigned int pk = (unsigned int)f2b(kv0) | ((unsigned int)f2b(kv1) << 16);
            ((unsigned int*)KdTg)[cb * 4096 + uidx] = pk;
        }
    }
}

// ---------------- triangular solves: (I+A)u = rhs, one column per thread -------
// grid (3, 512): part 0 -> Wp (rhs = scl0.K), parts 1,2 -> U (rhs = scl1.V).
// Default occupancy bound (round-7 lesson: (256,4) forced VGPR=64 -> u[] itself
// spilled, 716MB scratch traffic). sched_barrier(0) after each substitution row
// pins the schedule so the ~500 LDS Af loads can't be hoisted above the chain
// (round-6 lesson: unpinned, they inflate live set to 256 VGPR + 85MB spill).
__global__ __launch_bounds__(256) void solve_kernel(const unsigned short* __restrict__ kn,
                                                    const unsigned short* __restrict__ vn,
                                                    const float* __restrict__ Afg,
                                                    const float* __restrict__ scl0,
                                                    const float* __restrict__ scl1,
                                                    unsigned short* __restrict__ Wpg,
                                                    unsigned short* __restrict__ Ug) {
    int part = blockIdx.x;   // 0..2
    int cbi = blockIdx.y;    // 0..511
    int bh = cbi >> 5, nc = cbi & 31;
    int b = bh >> 2, h = bh & 3;
    int t0 = nc * 32;
    int tid = threadIdx.x;

    __shared__ float Af[32][33];
    __shared__ float s0[32];
#pragma unroll
    for (int i = 0; i < 4; ++i) {
        int e = i * 256 + tid;
        Af[e >> 5][e & 31] = Afg[(size_t)cbi * 1024 + e];
    }
    if (tid < 32)
        s0[tid] = (part == 0) ? scl0[(size_t)cbi * 32 + tid] : scl1[(size_t)cbi * 32 + tid];
    __syncthreads();

    float u[32];
    if (part == 0) {
#pragma unroll
        for (int r = 0; r < 32; ++r)
            u[r] = s0[r] * b2f(kn[((size_t)(b * T_ + t0 + r) * H_ + h) * DK_ + tid]);
    } else {
        int col = (part - 1) * 256 + tid;
#pragma unroll
        for (int r = 0; r < 32; ++r)
            u[r] = s0[r] * b2f(vn[((size_t)(b * T_ + t0 + r) * H_ + h) * DV_ + col]);
    }
#pragma unroll
    for (int r = 1; r < 32; ++r) {
        float a = 0.f;
#pragma unroll
        for (int l2 = 0; l2 < r; ++l2)
            a = fmaf(Af[r][l2], u[l2], a);
        u[r] -= a;
        __builtin_amdgcn_sched_barrier(0);  // pin: keep live set = u[] + one row
    }
    if (part == 0) {
#pragma unroll
        for (int r = 0; r < 32; ++r)
            Wpg[(size_t)cbi * 8192 + r * 256 + tid] = f2b(u[r]);
    } else {
        int col = (part - 1) * 256 + tid;
#pragma unroll
        for (int r = 0; r < 32; ++r)
            Ug[((size_t)cbi * 32 + r) * 512 + col] = f2b(u[r]);
    }
}

// ---------------- sequential pass: 512 blocks x 4 waves (k-split) --------------
__global__ __launch_bounds__(256) void seq_kernel(const unsigned short* __restrict__ qn,
                                                  const unsigned short* __restrict__ Wpg,
                                                  const unsigned short* __restrict__ KdTg,
                                                  const unsigned short* __restrict__ Pg,
                                                  const unsigned short* __restrict__ Ug,
                                                  const float* __restrict__ lambg,
                                                  unsigned short* __restrict__ o) {
    int blk = blockIdx.x;
    int vg = blk & 31, bh = blk >> 5;
    int b = bh >> 2, h = bh & 3;
    int tid = threadIdx.x;
    int w = tid >> 6, l = tid & 63;
    int vl = l & 15, hq = l >> 4;
    int v0 = vg * 16;

    __shared__ float Pu[4][32][17];
    __shared__ float Po[4][32][17];
    __shared__ __align__(16) unsigned short Ru[16][40];
    __shared__ float R2[4][64][17];

    float S[2][8] = {};

    for (int nc = 0; nc < 32; ++nc) {
        size_t cb = (size_t)bh * 32 + nc;
        int t0 = nc * 32;
        int ur_row = 8 * w + 2 * hq;
        float Ur0 = b2f(Ug[(cb * 32 + ur_row) * 512 + v0 + vl]);
        float Ur1 = b2f(Ug[(cb * 32 + ur_row + 1) * 512 + v0 + vl]);
        float lamC = lambg[cb * 32 + 31];
        float lmb[4];
        if (w < 2) {
#pragma unroll
            for (int r = 0; r < 4; ++r)
                lmb[r] = lambg[cb * 32 + 16 * w + 4 * hq + r];
        }
        short8_t bhi[2], blo[2];
#pragma unroll
        for (int kt = 0; kt < 2; ++kt)
#pragma unroll
            for (int j = 0; j < 8; ++j) {
                float sv = S[kt][j];
                unsigned short hh = f2b(sv);
                bhi[kt][j] = (short)hh;
                blo[kt][j] = (short)f2b(sv - b2f(hh));
            }
        floatx4 ua0 = {}, ua1 = {}, oa0 = {}, oa1 = {};
        const unsigned short* Wpc = Wpg + cb * 8192;
#pragma unroll
        for (int kt = 0; kt < 2; ++kt) {
            int kofs = w * 64 + kt * 32 + hq * 8;
            short8_t wa0 = *(const short8_t*)&Wpc[vl * 256 + kofs];
            short8_t wa1 = *(const short8_t*)&Wpc[(16 + vl) * 256 + kofs];
            short8_t qa0 = *(const short8_t*)&qn[((size_t)(b * T_ + t0 + vl) * H_ + h) * DK_ + kofs];
            short8_t qa1 = *(const short8_t*)&qn[((size_t)(b * T_ + t0 + 16 + vl) * H_ + h) * DK_ + kofs];
            ua0 = __builtin_amdgcn_mfma_f32_16x16x32_bf16(wa0, bhi[kt], ua0, 0, 0, 0);
            ua0 = __builtin_amdgcn_mfma_f32_16x16x32_bf16(wa0, blo[kt], ua0, 0, 0, 0);
            ua1 = __builtin_amdgcn_mfma_f32_16x16x32_bf16(wa1, bhi[kt], ua1, 0, 0, 0);
            ua1 = __builtin_amdgcn_mfma_f32_16x16x32_bf16(wa1, blo[kt], ua1, 0, 0, 0);
            oa0 = __builtin_amdgcn_mfma_f32_16x16x32_bf16(qa0, bhi[kt], oa0, 0, 0, 0);
            oa0 = __builtin_amdgcn_mfma_f32_16x16x32_bf16(qa0, blo[kt], oa0, 0, 0, 0);
            oa1 = __builtin_amdgcn_mfma_f32_16x16x32_bf16(qa1, bhi[kt], oa1, 0, 0, 0);
            oa1 = __builtin_amdgcn_mfma_f32_16x16x32_bf16(qa1, blo[kt], oa1, 0, 0, 0);
        }
#pragma unroll
        for (int r = 0; r < 4; ++r) {
            Pu[w][4 * hq + r][vl] = ua0[r];
            Pu[w][16 + 4 * hq + r][vl] = ua1[r];
            Po[w][4 * hq + r][vl] = oa0[r];
            Po[w][16 + 4 * hq + r][vl] = oa1[r];
        }
        __syncthreads();
#pragma unroll
        for (int j = 0; j < 2; ++j) {
            int r = ur_row + j;
            float s = Pu[0][r][vl] + Pu[1][r][vl] + Pu[2][r][vl] + Pu[3][r][vl];
            Ru[vl][r] = f2b(((j == 0) ? Ur0 : Ur1) - s);
        }
        __syncthreads();
        short8_t uf = *(const short8_t*)&Ru[vl][8 * hq];
        if (w < 2) {
            short8_t p = *(const short8_t*)&Pg[cb * 1024 + (w * 16 + vl) * 32 + hq * 8];
            floatx4 pa = {};
            pa = __builtin_amdgcn_mfma_f32_16x16x32_bf16(p, uf, pa, 0, 0, 0);
#pragma unroll
            for (int r = 0; r < 4; ++r) {
                int row = 16 * w + 4 * hq + r;
                float po = Po[0][row][vl] + Po[1][row][vl] + Po[2][row][vl] + Po[3][row][vl];
                o[((size_t)(b * T_ + t0 + row) * H_ + h) * DV_ + v0 + vl] =
                    f2b(0.0625f * (lmb[r] * po + pa[r]));
            }
        }
        const unsigned short* Kc = KdTg + cb * 8192;
#pragma unroll
        for (int kt = 0; kt < 4; ++kt) {
            short8_t ka = *(const short8_t*)&Kc[(w * 64 + kt * 16 + vl) * 32 + hq * 8];
            floatx4 sa = {};
            sa = __builtin_amdgcn_mfma_f32_16x16x32_bf16(ka, uf, sa, 0, 0, 0);
#pragma unroll
            for (int r = 0; r < 4; ++r)
                R2[w][kt * 16 + 4 * hq + r][vl] = sa[r];
        }
#pragma unroll
        for (int kt = 0; kt < 2; ++kt)
#pragma unroll
            for (int j = 0; j < 8; ++j)
                S[kt][j] = fmaf(lamC, S[kt][j], R2[w][kt * 32 + hq * 8 + j][vl]);
        __syncthreads();
    }
}

// ---------------- gated RMSNorm, in-place on bf16 o ----------------------------
__global__ __launch_bounds__(256) void gnorm_kernel(unsigned short* __restrict__ o,
                                                    const float* __restrict__ gate,
                                                    const float* __restrict__ norm_w) {
    int bth = blockIdx.x;
    int tid = threadIdx.x;
    unsigned short* orow = o + (size_t)bth * DV_;
    float v0 = b2f(orow[tid]), v1 = b2f(orow[256 + tid]);
    float ss = v0 * v0 + v1 * v1;
    for (int off = 32; off; off >>= 1) ss += __shfl_down(ss, off);
    __shared__ float ws4[4];
    int lane = tid & 63, wv = tid >> 6;
    if (lane == 0) ws4[wv] = ss;
    __syncthreads();
    float tot = ws4[0] + ws4[1] + ws4[2] + ws4[3];
    float r = rsqrtf(tot * (1.f / DV_) + 1e-5f);
    float g0 = gate[(size_t)bth * DV_ + tid];
    float g1 = gate[(size_t)bth * DV_ + 256 + tid];
    orow[tid] = f2b(v0 * r * norm_w[tid] * (g0 / (1.f + expf(-g0))));
    orow[256 + tid] = f2b(v1 * r * norm_w[256 + tid] * (g1 / (1.f + expf(-g1))));
}

extern "C" void kernel_launch(void* const* d_in, const int* in_sizes, int n_in,
                              void* d_out, int out_size, void* d_ws, size_t ws_size,
                              hipStream_t stream) {
    const float* x = (const float*)d_in[0];
    const float* Wq = (const float*)d_in[1];
    const float* Wk = (const float*)d_in[2];
    const float* Wv = (const float*)d_in[3];
    const float* cqw = (const float*)d_in[4];
    const float* ckw = (const float*)d_in[5];
    const float* cvw = (const float*)d_in[6];
    const float* Wb = (const float*)d_in[7];
    const float* Wa = (const float*)d_in[8];
    const float* A_log = (const float*)d_in[9];
    const float* dt_bias = (const float*)d_in[10];
    const float* Wg = (const float*)d_in[11];
    const float* norm_w = (const float*)d_in[12];
    const float* Wo = (const float*)d_in[13];
    float* out = (float*)d_out;

    float* ws = (float*)d_ws;
    const size_t M1 = (size_t)1024 * 1024;
    // lifetime-ordered regions (f32 offsets), peak ~30.1M floats:
    float* praw = ws;                                        // [0,16M) fused qkv gemm out (cols: q 0-1023, k 1024-2047, v 2048-4095)
    float* graw = ws;                                        // [0,8M)  gate gemm out (praw dead after convs), live to gnorm
    unsigned short* xb = (unsigned short*)(ws + 16 * M1);    // [16,18M) dead after g-gemm
    unsigned short* WcatT = (unsigned short*)(ws + 18 * M1); // [18,20M) [4096 rows,1024] bf16, dead after qkv gemm
    unsigned short* WgT = (unsigned short*)(ws + 20 * M1);   // [20,21M)
    unsigned short* WoT = (unsigned short*)(ws + 21 * M1);   // [21,22M) live to end
    unsigned short* qn = (unsigned short*)(ws + 22 * M1);    // [22,24M) live to seq
    unsigned short* kn = (unsigned short*)(ws + 24 * M1);    // [24,26M) dead after solve
    unsigned short* vn = (unsigned short*)(ws + 26 * M1);    // [26,30M) dead after solve
    float* g = ws + 30 * M1;                                 // [30M,+16K) dead after prep
    float* beta = g + 16384;                                 // +16K
    float* Afg = ws + 8 * M1;                                // [8,8.5M) dead after solve
    unsigned short* Pg = (unsigned short*)(ws + 8 * M1 + M1 / 2);   // [8.5,8.75M)
    unsigned short* KdTg = (unsigned short*)(ws + 9 * M1);   // [9,11M)
    float* lambg = ws + 11 * M1;                             // 16K
    float* scl0 = lambg + 16384;
    float* scl1 = scl0 + 16384;
    unsigned short* Wpg = (unsigned short*)(ws + 12 * M1);   // [12,14M)
    unsigned short* Ug = (unsigned short*)(ws + 14 * M1);    // [14,18M) (xb dead by then)
    unsigned short* ob = (unsigned short*)(ws + 24 * M1);    // [24,28M) seq out bf16 (kn/vn dead)

    dim3 blk(256);
    tob16_kernel<<<4096, blk, 0, stream>>>(x, xb);
    transpose_bf16_kernel<<<dim3(32, 32), blk, 0, stream>>>(Wq, WcatT, 1024, 1024);
    transpose_bf16_kernel<<<dim3(32, 32), blk, 0, stream>>>(Wk, WcatT + (size_t)1024 * 1024, 1024, 1024);
    transpose_bf16_kernel<<<dim3(64, 32), blk, 0, stream>>>(Wv, WcatT + (size_t)2048 * 1024, 1024, 2048);
    transpose_bf16_kernel<<<dim3(64, 32), blk, 0, stream>>>(Wg, WgT, 1024, 2048);
    transpose_bf16_kernel<<<dim3(32, 64), blk, 0, stream>>>(Wo, WoT, 2048, 1024);
    // fused q|k|v projection: [4096,1024] @ [1024,4096] -> praw (grid 32x32 = 1024 blocks)
    gemm_bf16_kernel<<<dim3(32, 32), blk, 0, stream>>>(xb, WcatT, praw, 4096, 4096, 1024);
    betag_kernel<<<4096, blk, 0, stream>>>(x, Wb, Wa, A_log, dt_bias, beta, g);
    convqk_kernel<<<16384, blk, 0, stream>>>(praw, 4096, cqw, (__hip_bfloat16*)qn);
    convqk_kernel<<<16384, blk, 0, stream>>>(praw + 1024, 4096, ckw, (__hip_bfloat16*)kn);
    convv_kernel<<<32768, blk, 0, stream>>>(praw + 2048, 4096, cvw, (__hip_bfloat16*)vn);
    // gate projection into freed praw region
    gemm_bf16_kernel<<<dim3(16, 32), blk, 0, stream>>>(xb, WgT, graw, 4096, 2048, 1024);
    prep_kernel<<<512, blk, 0, stream>>>(qn, kn, g, beta, Afg, KdTg, Pg, lambg, scl0, scl1);
    solve_kernel<<<dim3(3, 512), blk, 0, stream>>>(kn, vn, Afg, scl0, scl1, Wpg, Ug);
    seq_kernel<<<512, blk, 0, stream>>>(qn, Wpg, KdTg, Pg, Ug, lambg, ob);
    gnorm_kernel<<<16384, blk, 0, stream>>>(ob, graw, norm_w);
    gemm_bf16_kernel<<<dim3(8, 32), blk, 0, stream>>>(ob, WoT, out, 4096, 1024, 2048);
}